// Round 2
// baseline (1541.794 us; speedup 1.0000x reference)
//
#include <hip/hip_runtime.h>
#include <hip/hip_bf16.h>
#include <cstddef>

#define T_SEQ 512
#define BATCH 256
#define RTOT (BATCH * T_SEQ) /* 131072 rows */

__device__ __forceinline__ float fsigmoid(float x) {
    return 1.0f / (1.0f + __expf(-x));
}
__device__ __forceinline__ float ftanh(float x) {
    // tanh(x) = 1 - 2/(exp(2x)+1); saturates correctly at +-inf
    return 1.0f - 2.0f / (__expf(2.0f * x) + 1.0f);
}

// ---------------------------------------------------------------------------
// Input projection: xp[r, 0:192] = x[r, :] @ W + bi   for both directions.
// One block = 32 rows x 384 cols (f+b). X staged transposed in LDS so the
// inner loop reads 16B-aligned float4 broadcasts (all lanes same addr = free).
// ---------------------------------------------------------------------------
template <int DIN, bool EMBED>
__global__ __launch_bounds__(192) void proj_kernel(
    const float* __restrict__ X, const int* __restrict__ tokens,
    const float* __restrict__ emb,
    const float* __restrict__ Wf, const float* __restrict__ bf_,
    const float* __restrict__ Wb, const float* __restrict__ bb_,
    float* __restrict__ xpf, float* __restrict__ xpb)
{
    constexpr int ROWS = 32;
    constexpr int PAD = 36; // row stride 144B: 16B-aligned float4 reads
    __shared__ __align__(16) float xt[DIN][PAD];
    const int r0 = blockIdx.x * ROWS;
    const int tid = threadIdx.x;

    for (int e = tid; e < ROWS * DIN; e += 192) {
        const int row = e / DIN;
        const int i = e % DIN;
        float v;
        if (EMBED) {
            v = emb[(size_t)tokens[r0 + row] * 64 + i];
        } else {
            v = X[(size_t)(r0 + row) * DIN + i];
        }
        xt[i][row] = v;
    }
    __syncthreads();

    const int col = tid; // 0..191
    #pragma unroll
    for (int d = 0; d < 2; d++) {
        const float* __restrict__ W = d ? Wb : Wf;
        const float* __restrict__ bi = d ? bb_ : bf_;
        float* __restrict__ outp = d ? xpb : xpf;
        float acc[ROWS];
        const float b0 = bi[col];
        #pragma unroll
        for (int r = 0; r < ROWS; r++) acc[r] = b0;
        #pragma unroll 4
        for (int i = 0; i < DIN; i++) {
            const float w = W[i * 192 + col]; // coalesced, L1/L2-hot
            #pragma unroll
            for (int r = 0; r < ROWS; r += 4) {
                const float4 x4 = *(const float4*)&xt[i][r];
                acc[r + 0] = fmaf(x4.x, w, acc[r + 0]);
                acc[r + 1] = fmaf(x4.y, w, acc[r + 1]);
                acc[r + 2] = fmaf(x4.z, w, acc[r + 2]);
                acc[r + 3] = fmaf(x4.w, w, acc[r + 3]);
            }
        }
        #pragma unroll
        for (int r = 0; r < ROWS; r++) {
            outp[(size_t)(r0 + r) * 192 + col] = acc[r];
        }
    }
}

// ---------------------------------------------------------------------------
// Recurrent scan: one block (192 threads = 3 waves) per (batch, direction)
// chain. Thread k holds Wh[:,k] in 64 VGPRs. h in LDS (broadcast reads).
// wave0: z-gate, wave1: r-gate, wave2: candidate + state update + y write.
// Gate column order matches jnp.split: [0:64]=z, [64:128]=r, [128:192]=h.
// Masked steps (tok==0) carry state unchanged; y gets the carried state.
// ---------------------------------------------------------------------------
__global__ __launch_bounds__(192) void gru_scan(
    const float* __restrict__ xpf, const float* __restrict__ xpb,
    const float* __restrict__ whf, const float* __restrict__ whb,
    const float* __restrict__ bbf, const float* __restrict__ bbb,
    const int* __restrict__ tokens,
    float* __restrict__ y,        // [RTOT,128] or nullptr
    float* __restrict__ hfinal)   // [BATCH,128] or nullptr
{
    const int chain = blockIdx.x; // 0..511
    const int b = chain >> 1;
    const int dir = chain & 1;
    const float* __restrict__ xp = dir ? xpb : xpf;
    const float* __restrict__ wh = dir ? whb : whf;
    const float* __restrict__ bb = dir ? bbb : bbf;
    const int k = threadIdx.x; // 0..191 = gate column

    float whk[64];
    #pragma unroll
    for (int i = 0; i < 64; i++) whk[i] = wh[i * 192 + k];
    const float bhk = bb[192 + k]; // recurrent bias (bb row 1)

    __shared__ __align__(16) float h_lds[64];
    __shared__ float z_lds[64];
    __shared__ float r_lds[64];
    if (k < 64) h_lds[k] = 0.0f;
    __syncthreads();

    const int t0 = dir ? (T_SEQ - 1) : 0;
    const int st = dir ? -1 : 1;
    const size_t base = (size_t)b * T_SEQ;

    float xv = xp[(base + t0) * 192 + k];
    int tok = tokens[base + t0];

    for (int t = 0; t < T_SEQ; t++) {
        // prefetch next step's xp value + token (one full step to cover latency)
        const int tn = (t + 1 < T_SEQ) ? (t + 1) : t;
        const int te_n = t0 + st * tn;
        const float xv_n = xp[(base + te_n) * 192 + k];
        const int tok_n = tokens[base + te_n];

        // rec[k] = h . Wh[:,k] + bh[k]
        float acc = bhk;
        #pragma unroll
        for (int i = 0; i < 64; i += 4) {
            const float4 h4 = *(const float4*)&h_lds[i];
            acc = fmaf(h4.x, whk[i + 0], acc);
            acc = fmaf(h4.y, whk[i + 1], acc);
            acc = fmaf(h4.z, whk[i + 2], acc);
            acc = fmaf(h4.w, whk[i + 3], acc);
        }
        if (k < 64) {
            z_lds[k] = fsigmoid(xv + acc);          // wave0
        } else if (k < 128) {
            r_lds[k - 64] = fsigmoid(xv + acc);     // wave1
        }
        __syncthreads(); // gates visible
        if (k >= 128) {                             // wave2
            const int j = k - 128;
            const float r = r_lds[j];
            const float hh = ftanh(xv + r * acc);
            const float z = z_lds[j];
            const float hold = h_lds[j];
            float hnew = z * hold + (1.0f - z) * hh;
            if (!(tok > 0)) hnew = hold;            // Keras mask: carry state
            h_lds[j] = hnew;
            if (y) {
                const int te = t0 + st * t;
                y[(base + te) * 128 + (dir << 6) + j] = hnew;
            }
        }
        __syncthreads(); // new h visible
        xv = xv_n;
        tok = tok_n;
    }
    if (hfinal && k >= 128) {
        hfinal[b * 128 + (dir << 6) + (k - 128)] = h_lds[k - 128];
    }
}

// ---------------------------------------------------------------------------
// MLP head: one block (1 wave) per batch row.
// ---------------------------------------------------------------------------
__global__ __launch_bounds__(64) void mlp_kernel(
    const float* __restrict__ hcat, // [BATCH,128]
    const float* __restrict__ wd1, const float* __restrict__ bd1,
    const float* __restrict__ wd2, const float* __restrict__ bd2,
    const float* __restrict__ wd3, const float* __restrict__ bd3,
    const float* __restrict__ wo, const float* __restrict__ bo,
    float* __restrict__ outp)       // [BATCH,28]
{
    const int b = blockIdx.x;
    const int j = threadIdx.x; // 0..63
    __shared__ float x0[128];
    __shared__ float x1[64];
    x0[j] = hcat[b * 128 + j];
    x0[j + 64] = hcat[b * 128 + 64 + j];
    __syncthreads();
    float a = bd1[j];
    #pragma unroll 4
    for (int i = 0; i < 128; i++) a = fmaf(x0[i], wd1[i * 64 + j], a);
    a = fmaxf(a, 0.0f);
    x1[j] = a;
    __syncthreads();
    float a2 = bd2[j];
    #pragma unroll 4
    for (int i = 0; i < 64; i++) a2 = fmaf(x1[i], wd2[i * 64 + j], a2);
    a2 = fmaxf(a2, 0.0f);
    __syncthreads();
    x1[j] = a2;
    __syncthreads();
    float a3 = bd3[j];
    #pragma unroll 4
    for (int i = 0; i < 64; i++) a3 = fmaf(x1[i], wd3[i * 64 + j], a3);
    a3 = fmaxf(a3, 0.0f);
    __syncthreads();
    x1[j] = a3;
    __syncthreads();
    if (j < 28) {
        float o = bo[j];
        #pragma unroll 4
        for (int i = 0; i < 64; i++) o = fmaf(x1[i], wo[i * 28 + j], o);
        outp[b * 28 + j] = fsigmoid(o);
    }
}

// ---------------------------------------------------------------------------
extern "C" void kernel_launch(void* const* d_in, const int* in_sizes, int n_in,
                              void* d_out, int out_size, void* d_ws, size_t ws_size,
                              hipStream_t stream)
{
    const int* tokens  = (const int*)d_in[0];
    const float* emb   = (const float*)d_in[1];
    const float* wi1f  = (const float*)d_in[2];
    const float* wh1f  = (const float*)d_in[3];
    const float* bb1f  = (const float*)d_in[4];
    const float* wi1b  = (const float*)d_in[5];
    const float* wh1b  = (const float*)d_in[6];
    const float* bb1b  = (const float*)d_in[7];
    const float* wi2f  = (const float*)d_in[8];
    const float* wh2f  = (const float*)d_in[9];
    const float* bb2f  = (const float*)d_in[10];
    const float* wi2b  = (const float*)d_in[11];
    const float* wh2b  = (const float*)d_in[12];
    const float* bb2b  = (const float*)d_in[13];
    const float* wi3f  = (const float*)d_in[14];
    const float* wh3f  = (const float*)d_in[15];
    const float* bb3f  = (const float*)d_in[16];
    const float* wi3b  = (const float*)d_in[17];
    const float* wh3b  = (const float*)d_in[18];
    const float* bb3b  = (const float*)d_in[19];
    const float* wd1   = (const float*)d_in[20];
    const float* bd1   = (const float*)d_in[21];
    const float* wd2   = (const float*)d_in[22];
    const float* bd2   = (const float*)d_in[23];
    const float* wd3   = (const float*)d_in[24];
    const float* bd3   = (const float*)d_in[25];
    const float* wo    = (const float*)d_in[26];
    const float* bo    = (const float*)d_in[27];

    // Workspace layout (all fp32) — total EXACTLY 256 MiB:
    //   y    : RTOT*128  (layer output, reused)        67,108,864 B
    //   xpf  : RTOT*192  (fwd input projection)       100,663,296 B
    //   xpb  : RTOT*192  (bwd input projection)       100,663,296 B
    //   hcat : BATCH*128 — ALIASED onto y's space (y is dead after proj3
    //          reads it; the layer-3 scan writes only hfinal). Round 1
    //          placed hcat past 256 MiB -> OOB write -> abort.
    float* y    = (float*)d_ws;
    float* xpf  = y + (size_t)RTOT * 128;
    float* xpb  = xpf + (size_t)RTOT * 192;
    float* hcat = y; // alias: y region is dead by the time hcat is written

    const dim3 pb(192), pg(RTOT / 32);

    // Layer 1 (embedding fused into projection)
    proj_kernel<64, true><<<pg, pb, 0, stream>>>(nullptr, tokens, emb,
                                                 wi1f, bb1f, wi1b, bb1b, xpf, xpb);
    gru_scan<<<512, 192, 0, stream>>>(xpf, xpb, wh1f, wh1b, bb1f, bb1b,
                                      tokens, y, nullptr);
    // Layer 2
    proj_kernel<128, false><<<pg, pb, 0, stream>>>(y, nullptr, nullptr,
                                                   wi2f, bb2f, wi2b, bb2b, xpf, xpb);
    gru_scan<<<512, 192, 0, stream>>>(xpf, xpb, wh2f, wh2b, bb2f, bb2b,
                                      tokens, y, nullptr);
    // Layer 3 (final states only)
    proj_kernel<128, false><<<pg, pb, 0, stream>>>(y, nullptr, nullptr,
                                                   wi3f, bb3f, wi3b, bb3b, xpf, xpb);
    gru_scan<<<512, 192, 0, stream>>>(xpf, xpb, wh3f, wh3b, bb3f, bb3b,
                                      tokens, nullptr, hcat);
    // Head
    mlp_kernel<<<256, 64, 0, stream>>>(hcat, wd1, bd1, wd2, bd2, wd3, bd3,
                                       wo, bo, (float*)d_out);
}